// Round 1
// baseline (519.353 us; speedup 1.0000x reference)
//
#include <hip/hip_runtime.h>

// HashEmbedding (Instant-NGP multiresolution hash grid), MI355X gfx950.
// x: (2^20, 3) f32 ; tables: (16, 2^19, 2) f32 ; out: (2^20, 32) f32
// out[p][l*2+f] = trilinear interp of tables[l] at hashed corners.

#define NLVL 16
#define TMASK ((1u << 19) - 1u)
#define P1 2654435761u
#define P2 805459861u

__global__ __launch_bounds__(256)
void hash_embed_kernel(const float* __restrict__ x,
                       const float* __restrict__ tables,
                       float* __restrict__ out,
                       int n)
{
    const int p = blockIdx.x * 256 + threadIdx.x;
    if (p >= n) return;

    const float px = x[3 * p + 0];
    const float py = x[3 * p + 1];
    const float pz = x[3 * p + 2];
    // xn = (x - X_MIN) / (X_MAX - X_MIN) = (x + 1) / 2  (exact: pow-2 scale)
    const float xn0 = (px + 1.0f) * 0.5f;
    const float xn1 = (py + 1.0f) * 0.5f;
    const float xn2 = (pz + 1.0f) * 0.5f;

    // floor(16 * b^l), b = exp((ln512 - ln16)/15) = 2^(1/3)
    const float res[NLVL] = {16.f, 20.f, 25.f, 32.f, 40.f, 50.f, 64.f, 80.f,
                             101.f, 128.f, 161.f, 203.f, 256.f, 322.f, 406.f, 512.f};

    float4 o[8];
    float* ow = (float*)o;

#pragma unroll
    for (int l = 0; l < NLVL; ++l) {
        const float r = res[l];
        const float s0 = xn0 * r;
        const float s1 = xn1 * r;
        const float s2 = xn2 * r;
        const float f0 = floorf(s0);
        const float f1 = floorf(s1);
        const float f2 = floorf(s2);
        const float w0 = s0 - f0;
        const float w1 = s1 - f1;
        const float w2 = s2 - f2;
        const unsigned v0 = (unsigned)(int)f0;
        const unsigned v1 = (unsigned)(int)f1;
        const unsigned v2 = (unsigned)(int)f2;

        const float2* __restrict__ tab =
            (const float2*)tables + ((size_t)l << 19);

        const unsigned ax0 = v0;                  // prime 1
        const unsigned ax1 = v0 + 1u;
        const unsigned bx0 = v1 * P1;
        const unsigned bx1 = (v1 + 1u) * P1;
        const unsigned cx0 = v2 * P2;
        const unsigned cx1 = (v2 + 1u) * P2;

        // corner index c = i*4 + j*2 + k  (i over x, j over y, k over z)
        const float2 e0 = tab[(ax0 ^ bx0 ^ cx0) & TMASK];
        const float2 e1 = tab[(ax0 ^ bx0 ^ cx1) & TMASK];
        const float2 e2 = tab[(ax0 ^ bx1 ^ cx0) & TMASK];
        const float2 e3 = tab[(ax0 ^ bx1 ^ cx1) & TMASK];
        const float2 e4 = tab[(ax1 ^ bx0 ^ cx0) & TMASK];
        const float2 e5 = tab[(ax1 ^ bx0 ^ cx1) & TMASK];
        const float2 e6 = tab[(ax1 ^ bx1 ^ cx0) & TMASK];
        const float2 e7 = tab[(ax1 ^ bx1 ^ cx1) & TMASK];

        const float omx = 1.0f - w0;
        const float omy = 1.0f - w1;
        const float omz = 1.0f - w2;

        const float c00x = e0.x * omx + e4.x * w0;
        const float c00y = e0.y * omx + e4.y * w0;
        const float c01x = e1.x * omx + e5.x * w0;
        const float c01y = e1.y * omx + e5.y * w0;
        const float c10x = e2.x * omx + e6.x * w0;
        const float c10y = e2.y * omx + e6.y * w0;
        const float c11x = e3.x * omx + e7.x * w0;
        const float c11y = e3.y * omx + e7.y * w0;

        const float c0x = c00x * omy + c10x * w1;
        const float c0y = c00y * omy + c10y * w1;
        const float c1x = c01x * omy + c11x * w1;
        const float c1y = c01y * omy + c11y * w1;

        ow[2 * l + 0] = c0x * omz + c1x * w2;
        ow[2 * l + 1] = c0y * omz + c1y * w2;
    }

    float4* op = (float4*)(out + (size_t)p * 32);
#pragma unroll
    for (int q = 0; q < 8; ++q) op[q] = o[q];
}

extern "C" void kernel_launch(void* const* d_in, const int* in_sizes, int n_in,
                              void* d_out, int out_size, void* d_ws, size_t ws_size,
                              hipStream_t stream) {
    const float* x = (const float*)d_in[0];
    const float* tables = (const float*)d_in[1];
    float* out = (float*)d_out;
    const int n = in_sizes[0] / 3;             // 1048576 points
    const int blocks = (n + 255) / 256;        // 4096
    hash_embed_kernel<<<blocks, 256, 0, stream>>>(x, tables, out, n);
}

// Round 2
// 433.690 us; speedup vs baseline: 1.1975x; 1.1975x over previous
//
#include <hip/hip_runtime.h>

// HashEmbedding (Instant-NGP hash grid), MI355X gfx950.
// Round 2: level-pair partitioning for XCD-L2 locality + streaming transpose.
// x: (2^20, 3) f32 ; tables: (16, 2^19, 2) f32 ; out: (2^20, 32) f32

#define NLVL 16
#define TMASK ((1u << 19) - 1u)
#define P1 2654435761u
#define P2 805459861u

__constant__ float c_res[NLVL] = {16.f, 20.f, 25.f, 32.f, 40.f, 50.f, 64.f, 80.f,
                                  101.f, 128.f, 161.f, 203.f, 256.f, 322.f, 406.f, 512.f};

__device__ __forceinline__ void level_interp(float xn0, float xn1, float xn2,
                                             float r, const float2* __restrict__ tab,
                                             float& outx, float& outy)
{
    const float s0 = xn0 * r;
    const float s1 = xn1 * r;
    const float s2 = xn2 * r;
    const float f0 = floorf(s0);
    const float f1 = floorf(s1);
    const float f2 = floorf(s2);
    const float w0 = s0 - f0;
    const float w1 = s1 - f1;
    const float w2 = s2 - f2;
    const unsigned v0 = (unsigned)(int)f0;
    const unsigned v1 = (unsigned)(int)f1;
    const unsigned v2 = (unsigned)(int)f2;

    const unsigned ax0 = v0;
    const unsigned ax1 = v0 + 1u;
    const unsigned bx0 = v1 * P1;
    const unsigned bx1 = (v1 + 1u) * P1;
    const unsigned cx0 = v2 * P2;
    const unsigned cx1 = (v2 + 1u) * P2;

    const float2 e0 = tab[(ax0 ^ bx0 ^ cx0) & TMASK];
    const float2 e1 = tab[(ax0 ^ bx0 ^ cx1) & TMASK];
    const float2 e2 = tab[(ax0 ^ bx1 ^ cx0) & TMASK];
    const float2 e3 = tab[(ax0 ^ bx1 ^ cx1) & TMASK];
    const float2 e4 = tab[(ax1 ^ bx0 ^ cx0) & TMASK];
    const float2 e5 = tab[(ax1 ^ bx0 ^ cx1) & TMASK];
    const float2 e6 = tab[(ax1 ^ bx1 ^ cx0) & TMASK];
    const float2 e7 = tab[(ax1 ^ bx1 ^ cx1) & TMASK];

    const float omx = 1.0f - w0;
    const float omy = 1.0f - w1;
    const float omz = 1.0f - w2;

    const float c00x = e0.x * omx + e4.x * w0;
    const float c00y = e0.y * omx + e4.y * w0;
    const float c01x = e1.x * omx + e5.x * w0;
    const float c01y = e1.y * omx + e5.y * w0;
    const float c10x = e2.x * omx + e6.x * w0;
    const float c10y = e2.y * omx + e6.y * w0;
    const float c11x = e3.x * omx + e7.x * w0;
    const float c11y = e3.y * omx + e7.y * w0;

    const float c0x = c00x * omy + c10x * w1;
    const float c0y = c00y * omy + c10y * w1;
    const float c1x = c01x * omy + c11x * w1;
    const float c1y = c01y * omy + c11y * w1;

    outx = c0x * omz + c1x * w2;
    outy = c0y * omz + c1y * w2;
}

// ---- Kernel 1: gather, level-pair per block (pair q -> levels q and 15-q) ----
// ws[q][p] = {lvl q .x, .y, lvl 15-q .x, .y}
__global__ __launch_bounds__(256)
void k_gather(const float* __restrict__ x,
              const float* __restrict__ tables,
              float4* __restrict__ ws,
              int n)
{
    const int pair = blockIdx.x & 7;           // -> XCD id (round-robin dispatch)
    const int p = (blockIdx.x >> 3) * 256 + threadIdx.x;
    if (p >= n) return;

    const float xn0 = (x[3 * p + 0] + 1.0f) * 0.5f;
    const float xn1 = (x[3 * p + 1] + 1.0f) * 0.5f;
    const float xn2 = (x[3 * p + 2] + 1.0f) * 0.5f;

    const int lA = pair;
    const int lB = NLVL - 1 - pair;
    const float rA = c_res[lA];
    const float rB = c_res[lB];
    const float2* tabA = (const float2*)tables + ((size_t)lA << 19);
    const float2* tabB = (const float2*)tables + ((size_t)lB << 19);

    float4 o;
    level_interp(xn0, xn1, xn2, rA, tabA, o.x, o.y);
    level_interp(xn0, xn1, xn2, rB, tabB, o.z, o.w);

    ws[((size_t)pair << 20) + p] = o;   // 16B coalesced (n = 2^20)
}

// ---- Kernel 2: streaming transpose ws -> out ----
__global__ __launch_bounds__(256)
void k_transpose(const float4* __restrict__ ws,
                 float4* __restrict__ out,
                 int n)
{
    const int p = blockIdx.x * 256 + threadIdx.x;
    if (p >= n) return;

    float o[2 * NLVL];
#pragma unroll
    for (int q = 0; q < 8; ++q) {
        const float4 v = ws[((size_t)q << 20) + p];
        const int lA = q;
        const int lB = NLVL - 1 - q;
        o[2 * lA + 0] = v.x;
        o[2 * lA + 1] = v.y;
        o[2 * lB + 0] = v.z;
        o[2 * lB + 1] = v.w;
    }

    float4* op = out + (size_t)p * 8;
#pragma unroll
    for (int q = 0; q < 8; ++q)
        op[q] = make_float4(o[4 * q], o[4 * q + 1], o[4 * q + 2], o[4 * q + 3]);
}

// ---- Fallback: original single-kernel version (if ws too small) ----
__global__ __launch_bounds__(256)
void hash_embed_fallback(const float* __restrict__ x,
                         const float* __restrict__ tables,
                         float* __restrict__ out,
                         int n)
{
    const int p = blockIdx.x * 256 + threadIdx.x;
    if (p >= n) return;

    const float xn0 = (x[3 * p + 0] + 1.0f) * 0.5f;
    const float xn1 = (x[3 * p + 1] + 1.0f) * 0.5f;
    const float xn2 = (x[3 * p + 2] + 1.0f) * 0.5f;

    float o[2 * NLVL];
#pragma unroll
    for (int l = 0; l < NLVL; ++l) {
        const float2* tab = (const float2*)tables + ((size_t)l << 19);
        level_interp(xn0, xn1, xn2, c_res[l], tab, o[2 * l], o[2 * l + 1]);
    }

    float4* op = (float4*)(out + (size_t)p * 32);
#pragma unroll
    for (int q = 0; q < 8; ++q)
        op[q] = make_float4(o[4 * q], o[4 * q + 1], o[4 * q + 2], o[4 * q + 3]);
}

extern "C" void kernel_launch(void* const* d_in, const int* in_sizes, int n_in,
                              void* d_out, int out_size, void* d_ws, size_t ws_size,
                              hipStream_t stream) {
    const float* x = (const float*)d_in[0];
    const float* tables = (const float*)d_in[1];
    float* out = (float*)d_out;
    const int n = in_sizes[0] / 3;                 // 1048576 points
    const size_t ws_needed = (size_t)8 * (size_t)n * sizeof(float4);  // 128 MB

    if (ws_size >= ws_needed && n == (1 << 20)) {
        const int tiles = (n + 255) / 256;         // 4096
        k_gather<<<tiles * 8, 256, 0, stream>>>(x, tables, (float4*)d_ws, n);
        k_transpose<<<tiles, 256, 0, stream>>>((const float4*)d_ws, (float4*)out, n);
    } else {
        hash_embed_fallback<<<(n + 255) / 256, 256, 0, stream>>>(x, tables, out, n);
    }
}